// Round 3
// baseline (150.224 us; speedup 1.0000x reference)
//
#include <hip/hip_runtime.h>
#include <hip/hip_bf16.h>
#include <stdint.h>

typedef float  f32x4  __attribute__((ext_vector_type(4)));
typedef __bf16 bf16x8 __attribute__((ext_vector_type(8)));
typedef __bf16 bf16x4 __attribute__((ext_vector_type(4)));
typedef short  s16x8  __attribute__((ext_vector_type(8)));

static constexpr int Bc = 16, Sc = 512, Hc = 768, NSPAN = 4068;
static constexpr int BM = 128, BN = 256, BK = 64, KS = Hc / BK; // 12 k-steps

// ---------------- prep: W1^T -> bf16, LINEAR [n][k] layout (B is consumed global->reg now) ----------------
__global__ __launch_bounds__(256)
void prep_w1t(const float* __restrict__ w_lin, unsigned short* __restrict__ w1t) {
  __shared__ __align__(16) unsigned short T[64][80]; // [n_local][k_local], padded rows
  int bidk = blockIdx.x % 12, bidn = blockIdx.x / 12;
  int k0 = bidk * 64, n0 = bidn * 64;
  int tid = threadIdx.x;
#pragma unroll
  for (int p = 0; p < 16; ++p) {
    int idx = p * 256 + tid;
    int kl = idx >> 6, nl = idx & 63;
    float v = w_lin[(size_t)(k0 + kl) * Hc + (n0 + nl)];
    __bf16 bv = (__bf16)v;
    T[nl][kl] = __builtin_bit_cast(unsigned short, bv);
  }
  __syncthreads();
#pragma unroll
  for (int qq = 0; qq < 2; ++qq) {
    int q = qq * 256 + tid;
    int nl = q >> 3, c = q & 7;
    int n = n0 + nl;
    s16x8 v = *(const s16x8*)(&T[nl][c * 8]);
    *(s16x8*)(w1t + (size_t)n * Hc + k0 + c * 8) = v;
  }
}

// ---------------- cls projection (fp32 exact, bias folded) + token_inputs copy ----------------
__global__ __launch_bounds__(256)
void cls_proj_kernel(const float* __restrict__ emb, const float* __restrict__ w_lin,
                     const float* __restrict__ b_lin, float* __restrict__ out,
                     float* __restrict__ cls_proj) {
  __shared__ float cls_s[Hc];
  int b = blockIdx.x / 3, hc = blockIdx.x % 3;
  int tid = threadIdx.x;
  const float* cls = emb + (size_t)b * Sc * Hc; // row s=0
  for (int i = tid; i < Hc; i += 256) cls_s[i] = cls[i];
  __syncthreads();
  int h = hc * 256 + tid;
  const float* wp = w_lin + (size_t)Hc * Hc + h; // rows H..2H-1, column h
  float p0 = 0, p1 = 0, p2 = 0, p3 = 0, p4 = 0, p5 = 0, p6 = 0, p7 = 0;
  for (int f = 0; f < Hc; f += 8) {
    p0 += cls_s[f + 0] * wp[(size_t)(f + 0) * Hc];
    p1 += cls_s[f + 1] * wp[(size_t)(f + 1) * Hc];
    p2 += cls_s[f + 2] * wp[(size_t)(f + 2) * Hc];
    p3 += cls_s[f + 3] * wp[(size_t)(f + 3) * Hc];
    p4 += cls_s[f + 4] * wp[(size_t)(f + 4) * Hc];
    p5 += cls_s[f + 5] * wp[(size_t)(f + 5) * Hc];
    p6 += cls_s[f + 6] * wp[(size_t)(f + 6) * Hc];
    p7 += cls_s[f + 7] * wp[(size_t)(f + 7) * Hc];
  }
  float acc = b_lin[h] + (((p0 + p1) + (p2 + p3)) + ((p4 + p5) + (p6 + p7)));
  cls_proj[b * Hc + h] = acc;
  out[b * Hc + h] = cls_s[h]; // token_inputs
}

// ---------------- fused span-max + GEMM + epilogue ----------------
// Padded row space: m = (b*512 + s)*8 + (w-1). Tile = 128 rows (16 starts) x 256 cols.
// 4 waves, each wave computes the FULL 128 rows x its 64-col slice (acc 8x4 f32x4).
// A tile double-buffered in LDS (swizzled); B fragments loaded global->reg from L2-resident w1t.
// One raw s_barrier + lgkmcnt(0) per K-step; no vmcnt drain (no global_load_lds).
__global__ __launch_bounds__(256, 2)
void span_gemm(const float* __restrict__ emb, const unsigned short* __restrict__ w1t,
               const float* __restrict__ cls_proj, const float* __restrict__ w_lin,
               float* __restrict__ out) {
  __shared__ __align__(16) unsigned short Ald[2][BM * BK]; // 2 x 16 KB, swizzled [m][64] bf16

  int bid = blockIdx.x;
  int tile_n = bid % 3, tile_m = bid / 3;
  int b = tile_m >> 5;                 // 32 m-tiles per batch
  int s0 = (tile_m & 31) << 4;         // 16 starts per tile
  int n0 = tile_n * BN;
  int tid = threadIdx.x;
  int wid = tid >> 6, lane = tid & 63;
  int lq = lane >> 4, lr = lane & 15;

  const char* embC = (const char*)(emb + (size_t)b * Sc * Hc);

  // A-build item: start i = tid>>4 (0..15), k-quad = tid&15.
  int bi = tid >> 4, bkq = tid & 15;
  uint32_t rowoff[8];
#pragma unroll
  for (int t = 0; t < 8; ++t) {
    int r = s0 + bi + t;
    if (r > 511) r = 511; // clamped rows feed only discarded outputs
    rowoff[t] = (uint32_t)r * (Hc * 4) + bkq * 16;
  }
  int awbase = (bi << 10) + ((bkq & 1) << 3);

  // B fragment base: lane lr picks row, lq picks 16B k-chunk.
  const unsigned short* bbase = w1t + (size_t)(n0 + (wid << 6) + lr) * Hc + (lq << 3);

  f32x4 acc[8][4];
  f32x4 zer = {0.f, 0.f, 0.f, 0.f};
#pragma unroll
  for (int i = 0; i < 8; ++i)
#pragma unroll
    for (int j = 0; j < 4; ++j) acc[i][j] = zer;

  f32x4 rv[8];
  bf16x8 bfr[4][2]; // [ni][kk]

#define BUILD_A(dstbuf)                                                        \
  {                                                                            \
    f32x4 cm = rv[0];                                                          \
    _Pragma("unroll") for (int t = 0; t < 8; ++t) {                            \
      if (t) {                                                                 \
        cm[0] = fmaxf(cm[0], rv[t][0]);                                        \
        cm[1] = fmaxf(cm[1], rv[t][1]);                                        \
        cm[2] = fmaxf(cm[2], rv[t][2]);                                        \
        cm[3] = fmaxf(cm[3], rv[t][3]);                                        \
      }                                                                        \
      bf16x4 p;                                                                \
      p[0] = (__bf16)cm[0]; p[1] = (__bf16)cm[1];                              \
      p[2] = (__bf16)cm[2]; p[3] = (__bf16)cm[3];                              \
      int off = awbase + (t << 7) + ((((bkq >> 1) ^ t)) << 4);                 \
      *(uint2*)((char*)(dstbuf) + off) = __builtin_bit_cast(uint2, p);         \
    }                                                                          \
  }

  // ---- prologue: build A[0]; prefetch emb[1], B[0] ----
#pragma unroll
  for (int t = 0; t < 8; ++t) rv[t] = *(const f32x4*)(embC + rowoff[t]);
  BUILD_A(Ald[0]);
#pragma unroll
  for (int t = 0; t < 8; ++t) rv[t] = *(const f32x4*)(embC + rowoff[t] + 256);
#pragma unroll
  for (int ni = 0; ni < 4; ++ni)
#pragma unroll
    for (int kk = 0; kk < 2; ++kk)
      bfr[ni][kk] = *(const bf16x8*)(bbase + ni * 16 * Hc + kk * 32);
  asm volatile("s_waitcnt lgkmcnt(0)" ::: "memory");
  __builtin_amdgcn_sched_barrier(0);
  __builtin_amdgcn_s_barrier();

  for (int ks = 0; ks < KS; ++ks) {
    // ---- MFMA phase: read A frags from buf[ks&1], use prefetched B frags ----
    const char* abuf = (const char*)Ald[ks & 1];
#pragma unroll
    for (int kk = 0; kk < 2; ++kk) {
      bf16x8 af[8];
      int cf = (kk << 2) + lq;
#pragma unroll
      for (int mi = 0; mi < 8; ++mi) {
        int m = (mi << 4) + lr;
        af[mi] = *(const bf16x8*)(abuf + (m << 7) + ((cf ^ (m & 7)) << 4));
      }
#pragma unroll
      for (int mi = 0; mi < 8; ++mi)
#pragma unroll
        for (int ni = 0; ni < 4; ++ni)
          acc[mi][ni] = __builtin_amdgcn_mfma_f32_16x16x32_bf16(af[mi], bfr[ni][kk], acc[mi][ni], 0, 0, 0);
    }

    if (ks < KS - 1) {
      // ---- build A[ks+1] from prefetched rv; then prefetch emb[ks+2] and B[ks+1] ----
      BUILD_A(Ald[(ks + 1) & 1]);
      if (ks < KS - 2) {
#pragma unroll
        for (int t = 0; t < 8; ++t)
          rv[t] = *(const f32x4*)(embC + rowoff[t] + (ks + 2) * 256);
      }
#pragma unroll
      for (int ni = 0; ni < 4; ++ni)
#pragma unroll
        for (int kk = 0; kk < 2; ++kk)
          bfr[ni][kk] = *(const bf16x8*)(bbase + ni * 16 * Hc + (ks + 1) * 64 + kk * 32);
      asm volatile("s_waitcnt lgkmcnt(0)" ::: "memory");
      __builtin_amdgcn_sched_barrier(0);
      __builtin_amdgcn_s_barrier();
    }
  }

  // ---- epilogue: add cls_proj + width*w_last, map padded rows -> span index, store ----
  const float* w2p = w_lin + (size_t)(2 * Hc) * Hc; // row 2H of w_lin
  float* outp = out + Bc * Hc;                      // span_reps region
  int swb = (tile_m & 31) << 7;                     // s0*8
#pragma unroll
  for (int ni = 0; ni < 4; ++ni) {
    int h = n0 + (wid << 6) + (ni << 4) + lr;
    float cp = cls_proj[b * Hc + h];
    float w2 = w2p[h];
#pragma unroll
    for (int mi = 0; mi < 8; ++mi) {
#pragma unroll
      for (int j = 0; j < 4; ++j) {
        int m = (mi << 4) + (lq << 2) + j;
        int sw = swb + m;
        int s = sw >> 3, w = (sw & 7) + 1;
        if (s + w <= 512) {
          int nsp = (s <= 504) ? (sw)
                               : (NSPAN - (((512 - s) * (513 - s)) >> 1) + w - 1);
          size_t oidx = ((size_t)b * NSPAN + nsp) * Hc + h;
          outp[oidx] = acc[mi][ni][j] + cp + (float)w * w2;
        }
      }
    }
  }
}

extern "C" void kernel_launch(void* const* d_in, const int* in_sizes, int n_in,
                              void* d_out, int out_size, void* d_ws, size_t ws_size,
                              hipStream_t stream) {
  const float* emb = (const float*)d_in[0];
  const float* w_lin = (const float*)d_in[1];
  const float* b_lin = (const float*)d_in[2];
  unsigned short* w1t = (unsigned short*)d_ws;                   // 768*768 bf16 = 1.18 MB
  float* cls_proj = (float*)((char*)d_ws + (size_t)Hc * Hc * 2); // 16*768 f32
  float* out = (float*)d_out;

  hipLaunchKernelGGL(prep_w1t, dim3(144), dim3(256), 0, stream, w_lin, w1t);
  hipLaunchKernelGGL(cls_proj_kernel, dim3(48), dim3(256), 0, stream, emb, w_lin, b_lin, out, cls_proj);
  hipLaunchKernelGGL(span_gemm, dim3(512 * 3), dim3(256), 0, stream, emb, w1t, cls_proj, w_lin, out);
}